// Round 8
// baseline (287.380 us; speedup 1.0000x reference)
//
#include <hip/hip_runtime.h>
#include <cstdint>

// GRU recurrent autoencoder, MI355X persistent-MFMA implementation, round 14.
// B=2048, T=128, X=38, H=128, 3H=384. fp32 I/O, fp16 MFMA operands,
// fp32 accumulation + fp32 recurrent state (in registers).
//
// Round 14 = round 13 (286.7us harness best: native-exp2 weight folding +
// conflict-free stage_x + r11 scheduling) + decoder raw LDS barrier:
//  * DEC_STEP barrier is now "s_waitcnt lgkmcnt(0); s_barrier" (no vmcnt
//    drain). The two in-flight out[] stores per step no longer stall the
//    barrier (~50-150 cyc/step). Pattern is r7-proven with in-flight global
//    stores through the full harness; r8's replay-divergence config (spills
//    + register x-prefetch pipeline) is absent here (VGPR 92, x in LDS).
//  * Encoder + prep keep __syncthreads (encoder loop has zero global ops,
//    so its vmcnt(0) is already free).
// Structural levers verified dead this session: dup=4 (r9: 2x MFMA), any
// grid-128 regrouping (per-CU issue load unchanged, half chip idle), 1024-thr
// phase teams (full-WG barrier only on CDNA), sub-barrier h-exchange (the
// quad k-slices read all 8 waves' columns -> all-to-all each step).
// Kept from r10-r13: BT=8/grid 256 (dup=2 forced optimum), x in LDS fp16
// [t][8][40], HS=136, 2-step unrolled ping-pong h buffers, balanced 2+2
// MFMA chains, persistent C-init vectors, encoder x-GEMM shadow pipeline,
// S1/S2 exp2 weight folding with native v_exp_f32, decoder algebra (r/z
// folded dWhh+dWih*linW, n-gate W2 separate, proj at step top, t=0 pre-step).

#define T_SEQ 128
#define X_DIM 38
#define H_DIM 128
#define B_TOT 2048
#define BT    8
#define HS    136   // h row stride in halfs: 272B row stride -> 8-row spread
#define XK    40    // x row stride in halfs: 80B -> 8-row spread
#define XCH   64    // x chunk length (timesteps)

#define S1 1.44269504088896f   // log2(e)
#define S2 2.88539008177793f   // 2*log2(e)

#define HB_BYTES   (2 * BT * HS * 2)             // 4352
#define XC_BYTES   ((XCH + 1) * BT * XK * 2)     // 41600 (pad slot; >= 32768 w2lds)
#define SMEM_BYTES (HB_BYTES + XC_BYTES)         // 45952

typedef _Float16 half8 __attribute__((ext_vector_type(8)));
typedef float    f32x4 __attribute__((ext_vector_type(4)));

#define MF(a, b, c) __builtin_amdgcn_mfma_f32_16x16x32_f16((a), (b), (c), 0, 0, 0)

// LDS-only barrier: drains LDS ops, leaves global stores in flight.
// r7-proven pattern (full harness pass with in-flight out stores).
#define LDS_BARRIER() asm volatile("s_waitcnt lgkmcnt(0)\n\ts_barrier" ::: "memory")

// s pre-scaled by log2(e): sigmoid(x) = 1/(1+2^(-s)).  Native v_exp_f32.
__device__ __forceinline__ float sig2(float s) {
    return __builtin_amdgcn_rcpf(1.0f + __builtin_amdgcn_exp2f(-s));
}
// s pre-scaled by 2*log2(e): tanh(x) = 1 - 2/(1+2^s)
__device__ __forceinline__ float tanh2(float s) {
    return 1.0f - 2.0f * __builtin_amdgcn_rcpf(1.0f + __builtin_amdgcn_exp2f(s));
}

// compute x-part accumulators (bias-seeded) for local timestep TLOC
#define XG_CALC(TLOC, OUTr, OUTz, OUTn)                                        \
    do {                                                                       \
        const _Float16* xr_ = xchunk + ((TLOC) * BT + arow) * XK;              \
        half8 x0_ = *(const half8*)(xr_ + quad * 8);                           \
        half8 x1_ = *(const half8*)(xr_ + 32);                                 \
        OUTr = MF(x0_, wxe[0][0], vb_r);                                       \
        OUTr = MF(x1_, wxe[0][1], OUTr);                                       \
        OUTz = MF(x0_, wxe[1][0], vb_z);                                       \
        OUTz = MF(x1_, wxe[1][1], OUTz);                                       \
        OUTn = MF(x0_, wxe[2][0], vb_ngi);                                     \
        OUTn = MF(x1_, wxe[2][1], OUTn);                                       \
    } while (0)

// one encoder step: h(t) from HRD, x-part for t in IN*, h(t+1) -> HWR,
// x-part for t+1 -> OUT* (filled into the act/write shadow).
#define ENC_STEP(HRD, HWR, TLOC, INr, INz, INn, OUTr, OUTz, OUTn)              \
    do {                                                                       \
        const _Float16* xn_ = xchunk + (((TLOC) + 1) * BT + arow) * XK;        \
        half8 xn0_ = *(const half8*)(xn_ + quad * 8);                          \
        half8 xn1_ = *(const half8*)(xn_ + 32);                                \
        const _Float16* hb_ = (HRD) + arow * HS + quad * 8;                    \
        half8 h0_ = *(const half8*)(hb_ + 0 * 32);                             \
        half8 h1_ = *(const half8*)(hb_ + 1 * 32);                             \
        half8 h2_ = *(const half8*)(hb_ + 2 * 32);                             \
        half8 h3_ = *(const half8*)(hb_ + 3 * 32);                             \
        f32x4 ar_ = MF(h0_, wh[0][0], INr);                                    \
        ar_ = MF(h1_, wh[0][1], ar_);                                          \
        f32x4 arB_ = MF(h2_, wh[0][2], vzero);                                 \
        arB_ = MF(h3_, wh[0][3], arB_);                                        \
        f32x4 az_ = MF(h0_, wh[1][0], INz);                                    \
        az_ = MF(h1_, wh[1][1], az_);                                          \
        f32x4 azB_ = MF(h2_, wh[1][2], vzero);                                 \
        azB_ = MF(h3_, wh[1][3], azB_);                                        \
        f32x4 gn_ = MF(h0_, wh[2][0], vb_ngh);                                 \
        gn_ = MF(h1_, wh[2][1], gn_);                                          \
        f32x4 gnB_ = MF(h2_, wh[2][2], vzero);                                 \
        gnB_ = MF(h3_, wh[2][3], gnB_);                                        \
        _Pragma("unroll")                                                      \
        for (int e_ = 0; e_ < 2; ++e_) {                                       \
            const int rg_ = 2 * e_;   /* valid C rows: reg 0 / reg 2 */        \
            const float r_ = sig2(ar_[rg_] + arB_[rg_]);                       \
            const float z_ = sig2(az_[rg_] + azB_[rg_]);                       \
            const float n_ = tanh2(INn[rg_] + r_ * (gn_[rg_] + gnB_[rg_]));    \
            const float h_ = n_ + z_ * (hold[e_] - n_);                        \
            hold[e_] = h_;                                                     \
            (HWR)[(2 * quad + e_) * HS + j] = (_Float16)h_;                    \
        }                                                                      \
        OUTr = MF(xn0_, wxe[0][0], vb_r);       /* t+1 x-part: fills the */    \
        OUTr = MF(xn1_, wxe[0][1], OUTr);       /* act/write shadow      */    \
        OUTz = MF(xn0_, wxe[1][0], vb_z);                                      \
        OUTz = MF(xn1_, wxe[1][1], OUTz);                                      \
        OUTn = MF(xn0_, wxe[2][0], vb_ngi);                                    \
        OUTn = MF(xn1_, wxe[2][1], OUTn);                                      \
        __syncthreads();    /* encoder loop has no vmem ops: drain is free */  \
    } while (0)

// one decoder step: d(t) from HRD, d(t+1) -> HWR, o(TOUT) stored.
// Projection at the TOP (overlaps gate-GEMM issue), store immediate;
// raw LDS barrier leaves the store in flight across steps.
#define DEC_STEP(HRD, HWR, TOUT)                                               \
    do {                                                                       \
        const _Float16* hb_ = (HRD) + arow * HS + quad * 8;                    \
        half8 h0_ = *(const half8*)(hb_ + 0 * 32);                             \
        half8 h1_ = *(const half8*)(hb_ + 1 * 32);                             \
        half8 h2_ = *(const half8*)(hb_ + 2 * 32);                             \
        half8 h3_ = *(const half8*)(hb_ + 3 * 32);                             \
        if (wv < 3) {   /* o_{TOUT} = d @ linW^T + lb, split 2+2, store early */\
            f32x4 al_ = MF(h0_, wl[0], vb_lb);                                 \
            al_ = MF(h1_, wl[1], al_);                                         \
            f32x4 alB_ = MF(h2_, wl[2], vzero);                                \
            alB_ = MF(h3_, wl[3], alB_);                                       \
            if (nv) {                                                          \
                out[obase0 + (size_t)(TOUT) * X_DIM] = al_[0] + alB_[0];       \
                out[obase1 + (size_t)(TOUT) * X_DIM] = al_[2] + alB_[2];       \
            }                                                                  \
        }                                                                      \
        f32x4 ar_ = MF(h0_, wh[0][0], vd_r);                                   \
        ar_ = MF(h1_, wh[0][1], ar_);                                          \
        f32x4 arB_ = MF(h2_, wh[0][2], vzero);                                 \
        arB_ = MF(h3_, wh[0][3], arB_);                                        \
        f32x4 az_ = MF(h0_, wh[1][0], vd_z);                                   \
        az_ = MF(h1_, wh[1][1], az_);                                          \
        f32x4 azB_ = MF(h2_, wh[1][2], vzero);                                 \
        azB_ = MF(h3_, wh[1][3], azB_);                                        \
        f32x4 gn_ = MF(h0_, wh[2][0], vd_gh);                                  \
        gn_ = MF(h1_, wh[2][1], gn_);                                          \
        f32x4 gnB_ = MF(h2_, wh[2][2], vzero);                                 \
        gnB_ = MF(h3_, wh[2][3], gnB_);                                        \
        f32x4 gi_ = MF(h0_, wxn[0], vd_gi);                                    \
        gi_ = MF(h1_, wxn[1], gi_);                                            \
        f32x4 giB_ = MF(h2_, wxn[2], vzero);                                   \
        giB_ = MF(h3_, wxn[3], giB_);                                          \
        _Pragma("unroll")                                                      \
        for (int e_ = 0; e_ < 2; ++e_) {                                       \
            const int rg_ = 2 * e_;                                            \
            const float r_ = sig2(ar_[rg_] + arB_[rg_]);                       \
            const float z_ = sig2(az_[rg_] + azB_[rg_]);                       \
            const float n_ = tanh2((gi_[rg_] + giB_[rg_]) +                    \
                                   r_ * (gn_[rg_] + gnB_[rg_]));               \
            const float h_ = n_ + z_ * (hold[e_] - n_);                        \
            hold[e_] = h_;                                                     \
            (HWR)[(2 * quad + e_) * HS + j] = (_Float16)h_;                    \
        }                                                                      \
        LDS_BARRIER();   /* no vmcnt drain: out-stores pipeline across steps */\
    } while (0)

__global__ __launch_bounds__(512, 2)
void rae_gru_kernel(const float* __restrict__ x,
                    const float* __restrict__ eWih, const float* __restrict__ eWhh,
                    const float* __restrict__ ebih, const float* __restrict__ ebhh,
                    const float* __restrict__ dWih, const float* __restrict__ dWhh,
                    const float* __restrict__ dbih, const float* __restrict__ dbhh,
                    const float* __restrict__ linW, const float* __restrict__ linb,
                    float* __restrict__ out)
{
    __shared__ __align__(16) unsigned char smem[SMEM_BYTES];
    _Float16* const hbuf0  = (_Float16*)smem;                 // [BT][HS]
    _Float16* const hbuf1  = hbuf0 + BT * HS;                 // [BT][HS]
    _Float16* const xchunk = (_Float16*)(smem + HB_BYTES);    // [XCH+1][BT][XK]
    _Float16* const w2lds  = xchunk;                          // [128][128] alias (x dead)

    const int tid  = threadIdx.x;
    const int wv   = tid >> 6;        // 0..7
    const int ln   = tid & 63;
    const int quad = ln >> 4;         // A/B: k-group; C: row-group
    const int mrow = ln & 15;         // A: m-row / B,C: col-in-tile
    const int b0   = blockIdx.x * BT;
    const int arow = mrow >> 1;       // batch row this A-lane reads (b at m=2b)
    const int j    = wv * 16 + mrow;  // this lane's gate column (8 waves x 16)
    const int jc0  = j, jc1 = H_DIM + j, jc2 = 2 * H_DIM + j;

    {   // zero h buffers + whole x region (pad slot + pad cols stay 0)
        uint32_t* hz = (uint32_t*)smem;
        #pragma unroll 1
        for (int i = tid; i < SMEM_BYTES / 4; i += 512) hz[i] = 0u;
    }

    // ---- x chunk staging: sr=tid&7 (batch row), st=tid>>3 (timestep) ----
    // Neighbor threads differ in row: 80B stride -> 8 bank-quads, conflict-free.
    auto stage_x = [&](int tb) {
        const int sr = tid & 7, st = tid >> 3;
        const float* src = x + ((size_t)(b0 + sr) * T_SEQ + tb + st) * X_DIM;
        _Float16* dst = xchunk + ((size_t)st * BT + sr) * XK;
        float v[38];
        #pragma unroll
        for (int u = 0; u < 19; ++u) {
            float2 w = *(const float2*)(src + 2 * u);
            v[2 * u] = w.x; v[2 * u + 1] = w.y;
        }
        #pragma unroll
        for (int c = 0; c < 4; ++c) {
            half8 hv;
            #pragma unroll
            for (int e = 0; e < 8; ++e) hv[e] = (_Float16)v[c * 8 + e];
            *(half8*)(dst + c * 8) = hv;
        }
        {
            half8 hv;
            #pragma unroll
            for (int e = 0; e < 6; ++e) hv[e] = (_Float16)v[32 + e];
            hv[6] = (_Float16)0.0f; hv[7] = (_Float16)0.0f;
            *(half8*)(dst + 32) = hv;
        }
    };
    stage_x(0);

    // ---- persistent weight fragments (1 col-triple per wave) ----
    // r/z weights scaled by log2e, n-gate weights by 2*log2e (exp2 folding).
    half8 wh[3][4];    // enc: eWhh | dec: r/z combined, n pure dWhh
    half8 wxe[3][2];   // encoder Wih (K padded 38->64); dead after encoder
    half8 wxn[4];      // decoder n-gate W2
    half8 wl[4];       // linear head (UNscaled - linear output)
    const f32x4 vzero = { 0.f, 0.f, 0.f, 0.f };

    #pragma unroll
    for (int p = 0; p < 3; ++p) {
        const float sc = (p == 2) ? S2 : S1;
        const int jp = p * H_DIM + j;
        const float* wr = eWhh + (size_t)jp * H_DIM;
        #pragma unroll
        for (int c = 0; c < 4; ++c) {
            const int kb = c * 32 + quad * 8;
            half8 v;
            #pragma unroll
            for (int e = 0; e < 8; ++e) v[e] = (_Float16)(sc * wr[kb + e]);
            wh[p][c] = v;
        }
        const float* wir = eWih + (size_t)jp * X_DIM;
        #pragma unroll
        for (int c = 0; c < 2; ++c) {
            const int kb = c * 32 + quad * 8;
            half8 v;
            #pragma unroll
            for (int e = 0; e < 8; ++e) {
                const int k = kb + e;
                v[e] = (k < X_DIM) ? (_Float16)(sc * wir[k]) : (_Float16)0.0f;
            }
            wxe[p][c] = v;
        }
    }
    const float eb_r   = S1 * (ebih[jc0] + ebhh[jc0]);
    const float eb_z   = S1 * (ebih[jc1] + ebhh[jc1]);
    const float eb_ngi = S2 * ebih[jc2];
    const float eb_ngh = S2 * ebhh[jc2];
    const f32x4 vb_r   = { eb_r, eb_r, eb_r, eb_r };
    const f32x4 vb_z   = { eb_z, eb_z, eb_z, eb_z };
    const f32x4 vb_ngi = { eb_ngi, eb_ngi, eb_ngi, eb_ngi };
    const f32x4 vb_ngh = { eb_ngh, eb_ngh, eb_ngh, eb_ngh };

    float hold[2] = { 0.0f, 0.0f };   // h[2quad+e][j] in fp32

    __syncthreads();     // staging + zero complete

    // ================= encoder (2 chunks x 32 unrolled pairs) =============
    f32x4 xgAr, xgAz, xgAn, xgBr, xgBz, xgBn;
    #pragma unroll 1
    for (int ch = 0; ch < 2; ++ch) {
        XG_CALC(0, xgAr, xgAz, xgAn);
        #pragma unroll 1
        for (int i = 0; i < 32; ++i) {
            ENC_STEP(hbuf0, hbuf1, 2 * i,     xgAr, xgAz, xgAn, xgBr, xgBz, xgBn);
            ENC_STEP(hbuf1, hbuf0, 2 * i + 1, xgBr, xgBz, xgBn, xgAr, xgAz, xgAn);
        }
        // i=31 second step computed xgA from the zeroed pad slot -> junk,
        // discarded (recomputed at next chunk head / unused after chunk 2).
        if (ch == 0) {
            stage_x(XCH);
            __syncthreads();
        }
    }
    // h_enc now in hbuf0

    // ================= decoder weight prep =================
    // Step A: pure dWhh frags (scaled) + biases (scaled).
    #pragma unroll
    for (int p = 0; p < 3; ++p) {
        const float sc = (p == 2) ? S2 : S1;
        const float* wr = dWhh + (size_t)(p * H_DIM + j) * H_DIM;
        #pragma unroll
        for (int c = 0; c < 4; ++c) {
            const int kb = c * 32 + quad * 8;
            half8 v;
            #pragma unroll
            for (int e = 0; e < 8; ++e) v[e] = (_Float16)(sc * wr[kb + e]);
            wh[p][c] = v;
        }
    }
    const float c_r0 = S1 * (dbih[jc0] + dbhh[jc0]);
    const float c_z0 = S1 * (dbih[jc1] + dbhh[jc1]);
    const float c_n0 = S2 * dbih[jc2];
    const float d_ngh = S2 * dbhh[jc2];
    const f32x4 vd_gh = { d_ngh, d_ngh, d_ngh, d_ngh };

    // Step B: t=0 pre-step (gi = bias only). h_enc in hbuf0 -> d_1 to hbuf1.
    {
        const _Float16* hb_ = hbuf0 + arow * HS + quad * 8;
        half8 h0_ = *(const half8*)(hb_ + 0 * 32);
        half8 h1_ = *(const half8*)(hb_ + 1 * 32);
        half8 h2_ = *(const half8*)(hb_ + 2 * 32);
        half8 h3_ = *(const half8*)(hb_ + 3 * 32);
        f32x4 ar_ = { c_r0, c_r0, c_r0, c_r0 };
        ar_ = MF(h0_, wh[0][0], ar_);
        ar_ = MF(h1_, wh[0][1], ar_);
        f32x4 arB_ = MF(h2_, wh[0][2], vzero);
        arB_ = MF(h3_, wh[0][3], arB_);
        f32x4 az_ = { c_z0, c_z0, c_z0, c_z0 };
        az_ = MF(h0_, wh[1][0], az_);
        az_ = MF(h1_, wh[1][1], az_);
        f32x4 azB_ = MF(h2_, wh[1][2], vzero);
        azB_ = MF(h3_, wh[1][3], azB_);
        f32x4 gn_ = MF(h0_, wh[2][0], vd_gh);
        gn_ = MF(h1_, wh[2][1], gn_);
        f32x4 gnB_ = MF(h2_, wh[2][2], vzero);
        gnB_ = MF(h3_, wh[2][3], gnB_);
        #pragma unroll
        for (int e_ = 0; e_ < 2; ++e_) {
            const int rg_ = 2 * e_;
            const float r_ = sig2(ar_[rg_] + arB_[rg_]);
            const float z_ = sig2(az_[rg_] + azB_[rg_]);
            const float n_ = tanh2(c_n0 + r_ * (gn_[rg_] + gnB_[rg_]));
            const float h_ = n_ + z_ * (hold[e_] - n_);
            hold[e_] = h_;
            hbuf1[(2 * quad + e_) * HS + j] = (_Float16)h_;
        }
    }
    __syncthreads();

    // Step C: fold W2 = dWih*linW. r/z: wh <- fp16(S1*(dWhh + W2));
    // n: wxn <- fp16(S2*W2). (w2lds aliases xchunk; x is dead.)
    {
        const int kk = ((wv & 1) << 6) | ln;      // 0..127, lane's W2 column
        const int jb = (wv >> 1) * 32;            // 4 wave-pairs x 32 rows = 128
        float lc[X_DIM];
        #pragma unroll
        for (int m = 0; m < X_DIM; ++m) lc[m] = linW[m * H_DIM + kk];

        // gate 0 (r): combined
        #pragma unroll 1
        for (int jj = 0; jj < 32; ++jj) {
            const int jr = __builtin_amdgcn_readfirstlane(jb + jj);
            const float* dwr = dWih + (size_t)jr * X_DIM;
            float sacc = dWhh[(size_t)jr * H_DIM + kk];
            #pragma unroll
            for (int m = 0; m < X_DIM; ++m) sacc += dwr[m] * lc[m];
            w2lds[jr * H_DIM + kk] = (_Float16)(S1 * sacc);
        }
        __syncthreads();
        #pragma unroll
        for (int c = 0; c < 4; ++c)
            wh[0][c] = *(const half8*)&w2lds[j * H_DIM + c * 32 + quad * 8];
        __syncthreads();

        // gate 1 (z): combined
        #pragma unroll 1
        for (int jj = 0; jj < 32; ++jj) {
            const int jr = __builtin_amdgcn_readfirstlane(jb + jj);
            const float* dwr = dWih + (size_t)(H_DIM + jr) * X_DIM;
            float sacc = dWhh[(size_t)(H_DIM + jr) * H_DIM + kk];
            #pragma unroll
            for (int m = 0; m < X_DIM; ++m) sacc += dwr[m] * lc[m];
            w2lds[jr * H_DIM + kk] = (_Float16)(S1 * sacc);
        }
        __syncthreads();
        #pragma unroll
        for (int c = 0; c < 4; ++c)
            wh[1][c] = *(const half8*)&w2lds[j * H_DIM + c * 32 + quad * 8];
        __syncthreads();

        // gate 2 (n): W2 only (wh[2] stays pure scaled dWhh)
        #pragma unroll 1
        for (int jj = 0; jj < 32; ++jj) {
            const int jr = __builtin_amdgcn_readfirstlane(jb + jj);
            const float* dwr = dWih + (size_t)(2 * H_DIM + jr) * X_DIM;
            float sacc = 0.0f;
            #pragma unroll
            for (int m = 0; m < X_DIM; ++m) sacc += dwr[m] * lc[m];
            w2lds[jr * H_DIM + kk] = (_Float16)(S2 * sacc);
        }
        __syncthreads();
        #pragma unroll
        for (int c = 0; c < 4; ++c)
            wxn[c] = *(const half8*)&w2lds[j * H_DIM + c * 32 + quad * 8];
        __syncthreads();
    }

    // Step D: linear head frags + folded biases for t>=1.
    const int nlin = wv * 16 + mrow;          // waves 0..2 cover cols 0..47
    const bool nv = (wv < 3) && (nlin < X_DIM);
    float lb = 0.0f;
    {
        const float* lr = linW + (size_t)(nv ? nlin : 0) * H_DIM;
        #pragma unroll
        for (int c = 0; c < 4; ++c) {
            const int kb = c * 32 + quad * 8;
            half8 v;
            #pragma unroll
            for (int e = 0; e < 8; ++e)
                v[e] = nv ? (_Float16)lr[kb + e] : (_Float16)0.0f;
            wl[c] = v;
        }
        if (nv) lb = linb[nlin];
    }
    float db_r, db_z, db_gi;
    {
        float bf[3];
        #pragma unroll
        for (int p = 0; p < 3; ++p) {
            const float* dwr = dWih + (size_t)(p * H_DIM + j) * X_DIM;
            float sacc = 0.0f;
            #pragma unroll
            for (int m = 0; m < X_DIM; ++m) sacc += linb[m] * dwr[m];
            bf[p] = sacc;
        }
        db_r  = c_r0 + S1 * bf[0];
        db_z  = c_z0 + S1 * bf[1];
        db_gi = c_n0 + S2 * bf[2];
    }
    const f32x4 vd_r  = { db_r, db_r, db_r, db_r };
    const f32x4 vd_z  = { db_z, db_z, db_z, db_z };
    const f32x4 vd_gi = { db_gi, db_gi, db_gi, db_gi };
    const f32x4 vb_lb = { lb, lb, lb, lb };

    const size_t obase0 = ((size_t)(b0 + 2 * quad)     * T_SEQ) * X_DIM + nlin;
    const size_t obase1 = ((size_t)(b0 + 2 * quad + 1) * T_SEQ) * X_DIM + nlin;

    // ================= decoder (t=1..127, 63 unrolled pairs + tail) ========
    #pragma unroll 1
    for (int i = 0; i < 63; ++i) {
        DEC_STEP(hbuf1, hbuf0, 2 * i);        // t = 2i+1, stores o_{2i}
        DEC_STEP(hbuf0, hbuf1, 2 * i + 1);    // t = 2i+2, stores o_{2i+1}
    }
    DEC_STEP(hbuf1, hbuf0, 126);              // t = 127, stores o_126; d_128 -> hbuf0

    // tail projection: o_127 = d_128 @ linW^T + lb (d_128 in hbuf0; the
    // final LDS_BARRIER made those writes visible)
    if (wv < 3) {
        const _Float16* hb_ = hbuf0 + arow * HS + quad * 8;
        half8 h0_ = *(const half8*)(hb_ + 0 * 32);
        half8 h1_ = *(const half8*)(hb_ + 1 * 32);
        half8 h2_ = *(const half8*)(hb_ + 2 * 32);
        half8 h3_ = *(const half8*)(hb_ + 3 * 32);
        f32x4 al_ = MF(h0_, wl[0], vb_lb);
        al_ = MF(h1_, wl[1], al_);
        f32x4 alB_ = MF(h2_, wl[2], vzero);
        alB_ = MF(h3_, wl[3], alB_);
        if (nv) {
            out[obase0 + (size_t)(T_SEQ - 1) * X_DIM] = al_[0] + alB_[0];
            out[obase1 + (size_t)(T_SEQ - 1) * X_DIM] = al_[2] + alB_[2];
        }
    }
}

extern "C" void kernel_launch(void* const* d_in, const int* in_sizes, int n_in,
                              void* d_out, int out_size, void* d_ws, size_t ws_size,
                              hipStream_t stream) {
    (void)in_sizes; (void)n_in; (void)d_ws; (void)ws_size; (void)out_size;
    const float* x    = (const float*)d_in[0];
    const float* eWih = (const float*)d_in[1];
    const float* eWhh = (const float*)d_in[2];
    const float* ebih = (const float*)d_in[3];
    const float* ebhh = (const float*)d_in[4];
    const float* dWih = (const float*)d_in[5];
    const float* dWhh = (const float*)d_in[6];
    const float* dbih = (const float*)d_in[7];
    const float* dbhh = (const float*)d_in[8];
    const float* linW = (const float*)d_in[9];
    const float* linb = (const float*)d_in[10];
    float* out = (float*)d_out;

    rae_gru_kernel<<<dim3(B_TOT / BT), dim3(512), 0, stream>>>(
        x, eWih, eWhh, ebih, ebhh, dWih, dWhh, dbih, dbhh, linW, linb, out);
}

// Round 9
// 286.252 us; speedup vs baseline: 1.0039x; 1.0039x over previous
//
#include <hip/hip_runtime.h>
#include <cstdint>

// GRU recurrent autoencoder, MI355X persistent-MFMA implementation, round 15.
// B=2048, T=128, X=38, H=128, 3H=384. fp32 I/O, fp16 MFMA operands,
// fp32 accumulation + fp32 recurrent state (in registers).
//
// Round 15 = round 14 (best: 287.4us harness / 218.8us rocprof) with the
// decoder projection moved into the post-activation MFMA shadow:
//  * r12's deferred-proj was never isolated (its 18us regression is fully
//    accounted by the libm-exp2 VALU bloat, +180cyc/step). The deferral
//    itself mirrors the encoder's proven xg-shadow pipeline: proj MFMAs at
//    the step top delay the gate GEMM issue ~78cyc on waves 0-2 - exactly
//    the barrier-critical waves (they carry 20 MFMAs vs 16 on waves 3-7).
//  * New DEC_STEP order: ds_read h -> gate GEMM -> activation + h-write ->
//    proj + IMMEDIATE store -> raw LDS barrier. With the r14 lgkmcnt-only
//    barrier there is no vmcnt drain anywhere, so the store needs no
//    deferral to the next step (r12's po-carry structure is unnecessary).
//    Critical path loses the 4 proj-MFMA issues; proj fills the shadow
//    where waves 3-7 idle anyway.
// Kept from r10-r14: BT=8/grid 256 (dup=2 forced optimum per r9), x in LDS
// fp16 [t][8][40], HS=136, 2-step unrolled ping-pong h buffers, balanced
// 2+2 MFMA chains, persistent C-init vectors, encoder x-GEMM shadow
// pipeline, S1/S2 exp2 weight folding with native v_exp_f32, conflict-free
// stage_x, raw LDS barrier in decoder, __syncthreads in encoder/prep,
// decoder algebra (r/z folded dWhh+dWih*linW, n-gate W2 separate, t=0
// pre-step).
// Structural levers verified dead: dup=4 (r9), grid-128 regroupings,
// 1024-thr phase teams (no named barriers), sub-barrier h-exchange
// (all-to-all). Floor accounting: MFMA pipe 776cyc/SIMD/step vs wall
// ~2120cyc - the rest is lockstep latency at forced 1 WG/CU.

#define T_SEQ 128
#define X_DIM 38
#define H_DIM 128
#define B_TOT 2048
#define BT    8
#define HS    136   // h row stride in halfs: 272B row stride -> 8-row spread
#define XK    40    // x row stride in halfs: 80B -> 8-row spread
#define XCH   64    // x chunk length (timesteps)

#define S1 1.44269504088896f   // log2(e)
#define S2 2.88539008177793f   // 2*log2(e)

#define HB_BYTES   (2 * BT * HS * 2)             // 4352
#define XC_BYTES   ((XCH + 1) * BT * XK * 2)     // 41600 (pad slot; >= 32768 w2lds)
#define SMEM_BYTES (HB_BYTES + XC_BYTES)         // 45952

typedef _Float16 half8 __attribute__((ext_vector_type(8)));
typedef float    f32x4 __attribute__((ext_vector_type(4)));

#define MF(a, b, c) __builtin_amdgcn_mfma_f32_16x16x32_f16((a), (b), (c), 0, 0, 0)

// LDS-only barrier: drains LDS ops, leaves global stores in flight.
// r7/r14-proven pattern (full harness pass with in-flight out stores).
#define LDS_BARRIER() asm volatile("s_waitcnt lgkmcnt(0)\n\ts_barrier" ::: "memory")

// s pre-scaled by log2(e): sigmoid(x) = 1/(1+2^(-s)).  Native v_exp_f32.
__device__ __forceinline__ float sig2(float s) {
    return __builtin_amdgcn_rcpf(1.0f + __builtin_amdgcn_exp2f(-s));
}
// s pre-scaled by 2*log2(e): tanh(x) = 1 - 2/(1+2^s)
__device__ __forceinline__ float tanh2(float s) {
    return 1.0f - 2.0f * __builtin_amdgcn_rcpf(1.0f + __builtin_amdgcn_exp2f(s));
}

// compute x-part accumulators (bias-seeded) for local timestep TLOC
#define XG_CALC(TLOC, OUTr, OUTz, OUTn)                                        \
    do {                                                                       \
        const _Float16* xr_ = xchunk + ((TLOC) * BT + arow) * XK;              \
        half8 x0_ = *(const half8*)(xr_ + quad * 8);                           \
        half8 x1_ = *(const half8*)(xr_ + 32);                                 \
        OUTr = MF(x0_, wxe[0][0], vb_r);                                       \
        OUTr = MF(x1_, wxe[0][1], OUTr);                                       \
        OUTz = MF(x0_, wxe[1][0], vb_z);                                       \
        OUTz = MF(x1_, wxe[1][1], OUTz);                                       \
        OUTn = MF(x0_, wxe[2][0], vb_ngi);                                     \
        OUTn = MF(x1_, wxe[2][1], OUTn);                                       \
    } while (0)

// one encoder step: h(t) from HRD, x-part for t in IN*, h(t+1) -> HWR,
// x-part for t+1 -> OUT* (filled into the act/write shadow).
#define ENC_STEP(HRD, HWR, TLOC, INr, INz, INn, OUTr, OUTz, OUTn)              \
    do {                                                                       \
        const _Float16* xn_ = xchunk + (((TLOC) + 1) * BT + arow) * XK;        \
        half8 xn0_ = *(const half8*)(xn_ + quad * 8);                          \
        half8 xn1_ = *(const half8*)(xn_ + 32);                                \
        const _Float16* hb_ = (HRD) + arow * HS + quad * 8;                    \
        half8 h0_ = *(const half8*)(hb_ + 0 * 32);                             \
        half8 h1_ = *(const half8*)(hb_ + 1 * 32);                             \
        half8 h2_ = *(const half8*)(hb_ + 2 * 32);                             \
        half8 h3_ = *(const half8*)(hb_ + 3 * 32);                             \
        f32x4 ar_ = MF(h0_, wh[0][0], INr);                                    \
        ar_ = MF(h1_, wh[0][1], ar_);                                          \
        f32x4 arB_ = MF(h2_, wh[0][2], vzero);                                 \
        arB_ = MF(h3_, wh[0][3], arB_);                                        \
        f32x4 az_ = MF(h0_, wh[1][0], INz);                                    \
        az_ = MF(h1_, wh[1][1], az_);                                          \
        f32x4 azB_ = MF(h2_, wh[1][2], vzero);                                 \
        azB_ = MF(h3_, wh[1][3], azB_);                                        \
        f32x4 gn_ = MF(h0_, wh[2][0], vb_ngh);                                 \
        gn_ = MF(h1_, wh[2][1], gn_);                                          \
        f32x4 gnB_ = MF(h2_, wh[2][2], vzero);                                 \
        gnB_ = MF(h3_, wh[2][3], gnB_);                                        \
        _Pragma("unroll")                                                      \
        for (int e_ = 0; e_ < 2; ++e_) {                                       \
            const int rg_ = 2 * e_;   /* valid C rows: reg 0 / reg 2 */        \
            const float r_ = sig2(ar_[rg_] + arB_[rg_]);                       \
            const float z_ = sig2(az_[rg_] + azB_[rg_]);                       \
            const float n_ = tanh2(INn[rg_] + r_ * (gn_[rg_] + gnB_[rg_]));    \
            const float h_ = n_ + z_ * (hold[e_] - n_);                        \
            hold[e_] = h_;                                                     \
            (HWR)[(2 * quad + e_) * HS + j] = (_Float16)h_;                    \
        }                                                                      \
        OUTr = MF(xn0_, wxe[0][0], vb_r);       /* t+1 x-part: fills the */    \
        OUTr = MF(xn1_, wxe[0][1], OUTr);       /* act/write shadow      */    \
        OUTz = MF(xn0_, wxe[1][0], vb_z);                                      \
        OUTz = MF(xn1_, wxe[1][1], OUTz);                                      \
        OUTn = MF(xn0_, wxe[2][0], vb_ngi);                                    \
        OUTn = MF(xn1_, wxe[2][1], OUTn);                                      \
        __syncthreads();    /* encoder loop has no vmem ops: drain is free */  \
    } while (0)

// one decoder step: d(t) from HRD, d(t+1) -> HWR, o(TOUT) stored.
// Gate GEMM FIRST (critical path starts immediately); projection runs in
// the post-activation shadow (where waves 3-7 idle) with immediate store;
// raw LDS barrier leaves the store in flight across steps.
#define DEC_STEP(HRD, HWR, TOUT)                                               \
    do {                                                                       \
        const _Float16* hb_ = (HRD) + arow * HS + quad * 8;                    \
        half8 h0_ = *(const half8*)(hb_ + 0 * 32);                             \
        half8 h1_ = *(const half8*)(hb_ + 1 * 32);                             \
        half8 h2_ = *(const half8*)(hb_ + 2 * 32);                             \
        half8 h3_ = *(const half8*)(hb_ + 3 * 32);                             \
        f32x4 ar_ = MF(h0_, wh[0][0], vd_r);                                   \
        ar_ = MF(h1_, wh[0][1], ar_);                                          \
        f32x4 arB_ = MF(h2_, wh[0][2], vzero);                                 \
        arB_ = MF(h3_, wh[0][3], arB_);                                        \
        f32x4 az_ = MF(h0_, wh[1][0], vd_z);                                   \
        az_ = MF(h1_, wh[1][1], az_);                                          \
        f32x4 azB_ = MF(h2_, wh[1][2], vzero);                                 \
        azB_ = MF(h3_, wh[1][3], azB_);                                        \
        f32x4 gn_ = MF(h0_, wh[2][0], vd_gh);                                  \
        gn_ = MF(h1_, wh[2][1], gn_);                                          \
        f32x4 gnB_ = MF(h2_, wh[2][2], vzero);                                 \
        gnB_ = MF(h3_, wh[2][3], gnB_);                                        \
        f32x4 gi_ = MF(h0_, wxn[0], vd_gi);                                    \
        gi_ = MF(h1_, wxn[1], gi_);                                            \
        f32x4 giB_ = MF(h2_, wxn[2], vzero);                                   \
        giB_ = MF(h3_, wxn[3], giB_);                                          \
        _Pragma("unroll")                                                      \
        for (int e_ = 0; e_ < 2; ++e_) {                                       \
            const int rg_ = 2 * e_;                                            \
            const float r_ = sig2(ar_[rg_] + arB_[rg_]);                       \
            const float z_ = sig2(az_[rg_] + azB_[rg_]);                       \
            const float n_ = tanh2((gi_[rg_] + giB_[rg_]) +                    \
                                   r_ * (gn_[rg_] + gnB_[rg_]));               \
            const float h_ = n_ + z_ * (hold[e_] - n_);                        \
            hold[e_] = h_;                                                     \
            (HWR)[(2 * quad + e_) * HS + j] = (_Float16)h_;                    \
        }                                                                      \
        if (wv < 3) {   /* proj in the post-activation shadow, store now */    \
            f32x4 al_ = MF(h0_, wl[0], vb_lb);                                 \
            al_ = MF(h1_, wl[1], al_);                                         \
            f32x4 alB_ = MF(h2_, wl[2], vzero);                                \
            alB_ = MF(h3_, wl[3], alB_);                                       \
            if (nv) {                                                          \
                out[obase0 + (size_t)(TOUT) * X_DIM] = al_[0] + alB_[0];       \
                out[obase1 + (size_t)(TOUT) * X_DIM] = al_[2] + alB_[2];       \
            }                                                                  \
        }                                                                      \
        LDS_BARRIER();   /* no vmcnt drain: out-stores pipeline across steps */\
    } while (0)

__global__ __launch_bounds__(512, 2)
void rae_gru_kernel(const float* __restrict__ x,
                    const float* __restrict__ eWih, const float* __restrict__ eWhh,
                    const float* __restrict__ ebih, const float* __restrict__ ebhh,
                    const float* __restrict__ dWih, const float* __restrict__ dWhh,
                    const float* __restrict__ dbih, const float* __restrict__ dbhh,
                    const float* __restrict__ linW, const float* __restrict__ linb,
                    float* __restrict__ out)
{
    __shared__ __align__(16) unsigned char smem[SMEM_BYTES];
    _Float16* const hbuf0  = (_Float16*)smem;                 // [BT][HS]
    _Float16* const hbuf1  = hbuf0 + BT * HS;                 // [BT][HS]
    _Float16* const xchunk = (_Float16*)(smem + HB_BYTES);    // [XCH+1][BT][XK]
    _Float16* const w2lds  = xchunk;                          // [128][128] alias (x dead)

    const int tid  = threadIdx.x;
    const int wv   = tid >> 6;        // 0..7
    const int ln   = tid & 63;
    const int quad = ln >> 4;         // A/B: k-group; C: row-group
    const int mrow = ln & 15;         // A: m-row / B,C: col-in-tile
    const int b0   = blockIdx.x * BT;
    const int arow = mrow >> 1;       // batch row this A-lane reads (b at m=2b)
    const int j    = wv * 16 + mrow;  // this lane's gate column (8 waves x 16)
    const int jc0  = j, jc1 = H_DIM + j, jc2 = 2 * H_DIM + j;

    {   // zero h buffers + whole x region (pad slot + pad cols stay 0)
        uint32_t* hz = (uint32_t*)smem;
        #pragma unroll 1
        for (int i = tid; i < SMEM_BYTES / 4; i += 512) hz[i] = 0u;
    }

    // ---- x chunk staging: sr=tid&7 (batch row), st=tid>>3 (timestep) ----
    // Neighbor threads differ in row: 80B stride -> 8 bank-quads, conflict-free.
    auto stage_x = [&](int tb) {
        const int sr = tid & 7, st = tid >> 3;
        const float* src = x + ((size_t)(b0 + sr) * T_SEQ + tb + st) * X_DIM;
        _Float16* dst = xchunk + ((size_t)st * BT + sr) * XK;
        float v[38];
        #pragma unroll
        for (int u = 0; u < 19; ++u) {
            float2 w = *(const float2*)(src + 2 * u);
            v[2 * u] = w.x; v[2 * u + 1] = w.y;
        }
        #pragma unroll
        for (int c = 0; c < 4; ++c) {
            half8 hv;
            #pragma unroll
            for (int e = 0; e < 8; ++e) hv[e] = (_Float16)v[c * 8 + e];
            *(half8*)(dst + c * 8) = hv;
        }
        {
            half8 hv;
            #pragma unroll
            for (int e = 0; e < 6; ++e) hv[e] = (_Float16)v[32 + e];
            hv[6] = (_Float16)0.0f; hv[7] = (_Float16)0.0f;
            *(half8*)(dst + 32) = hv;
        }
    };
    stage_x(0);

    // ---- persistent weight fragments (1 col-triple per wave) ----
    // r/z weights scaled by log2e, n-gate weights by 2*log2e (exp2 folding).
    half8 wh[3][4];    // enc: eWhh | dec: r/z combined, n pure dWhh
    half8 wxe[3][2];   // encoder Wih (K padded 38->64); dead after encoder
    half8 wxn[4];      // decoder n-gate W2
    half8 wl[4];       // linear head (UNscaled - linear output)
    const f32x4 vzero = { 0.f, 0.f, 0.f, 0.f };

    #pragma unroll
    for (int p = 0; p < 3; ++p) {
        const float sc = (p == 2) ? S2 : S1;
        const int jp = p * H_DIM + j;
        const float* wr = eWhh + (size_t)jp * H_DIM;
        #pragma unroll
        for (int c = 0; c < 4; ++c) {
            const int kb = c * 32 + quad * 8;
            half8 v;
            #pragma unroll
            for (int e = 0; e < 8; ++e) v[e] = (_Float16)(sc * wr[kb + e]);
            wh[p][c] = v;
        }
        const float* wir = eWih + (size_t)jp * X_DIM;
        #pragma unroll
        for (int c = 0; c < 2; ++c) {
            const int kb = c * 32 + quad * 8;
            half8 v;
            #pragma unroll
            for (int e = 0; e < 8; ++e) {
                const int k = kb + e;
                v[e] = (k < X_DIM) ? (_Float16)(sc * wir[k]) : (_Float16)0.0f;
            }
            wxe[p][c] = v;
        }
    }
    const float eb_r   = S1 * (ebih[jc0] + ebhh[jc0]);
    const float eb_z   = S1 * (ebih[jc1] + ebhh[jc1]);
    const float eb_ngi = S2 * ebih[jc2];
    const float eb_ngh = S2 * ebhh[jc2];
    const f32x4 vb_r   = { eb_r, eb_r, eb_r, eb_r };
    const f32x4 vb_z   = { eb_z, eb_z, eb_z, eb_z };
    const f32x4 vb_ngi = { eb_ngi, eb_ngi, eb_ngi, eb_ngi };
    const f32x4 vb_ngh = { eb_ngh, eb_ngh, eb_ngh, eb_ngh };

    float hold[2] = { 0.0f, 0.0f };   // h[2quad+e][j] in fp32

    __syncthreads();     // staging + zero complete

    // ================= encoder (2 chunks x 32 unrolled pairs) =============
    f32x4 xgAr, xgAz, xgAn, xgBr, xgBz, xgBn;
    #pragma unroll 1
    for (int ch = 0; ch < 2; ++ch) {
        XG_CALC(0, xgAr, xgAz, xgAn);
        #pragma unroll 1
        for (int i = 0; i < 32; ++i) {
            ENC_STEP(hbuf0, hbuf1, 2 * i,     xgAr, xgAz, xgAn, xgBr, xgBz, xgBn);
            ENC_STEP(hbuf1, hbuf0, 2 * i + 1, xgBr, xgBz, xgBn, xgAr, xgAz, xgAn);
        }
        // i=31 second step computed xgA from the zeroed pad slot -> junk,
        // discarded (recomputed at next chunk head / unused after chunk 2).
        if (ch == 0) {
            stage_x(XCH);
            __syncthreads();
        }
    }
    // h_enc now in hbuf0

    // ================= decoder weight prep =================
    // Step A: pure dWhh frags (scaled) + biases (scaled).
    #pragma unroll
    for (int p = 0; p < 3; ++p) {
        const float sc = (p == 2) ? S2 : S1;
        const float* wr = dWhh + (size_t)(p * H_DIM + j) * H_DIM;
        #pragma unroll
        for (int c = 0; c < 4; ++c) {
            const int kb = c * 32 + quad * 8;
            half8 v;
            #pragma unroll
            for (int e = 0; e < 8; ++e) v[e] = (_Float16)(sc * wr[kb + e]);
            wh[p][c] = v;
        }
    }
    const float c_r0 = S1 * (dbih[jc0] + dbhh[jc0]);
    const float c_z0 = S1 * (dbih[jc1] + dbhh[jc1]);
    const float c_n0 = S2 * dbih[jc2];
    const float d_ngh = S2 * dbhh[jc2];
    const f32x4 vd_gh = { d_ngh, d_ngh, d_ngh, d_ngh };

    // Step B: t=0 pre-step (gi = bias only). h_enc in hbuf0 -> d_1 to hbuf1.
    {
        const _Float16* hb_ = hbuf0 + arow * HS + quad * 8;
        half8 h0_ = *(const half8*)(hb_ + 0 * 32);
        half8 h1_ = *(const half8*)(hb_ + 1 * 32);
        half8 h2_ = *(const half8*)(hb_ + 2 * 32);
        half8 h3_ = *(const half8*)(hb_ + 3 * 32);
        f32x4 ar_ = { c_r0, c_r0, c_r0, c_r0 };
        ar_ = MF(h0_, wh[0][0], ar_);
        ar_ = MF(h1_, wh[0][1], ar_);
        f32x4 arB_ = MF(h2_, wh[0][2], vzero);
        arB_ = MF(h3_, wh[0][3], arB_);
        f32x4 az_ = { c_z0, c_z0, c_z0, c_z0 };
        az_ = MF(h0_, wh[1][0], az_);
        az_ = MF(h1_, wh[1][1], az_);
        f32x4 azB_ = MF(h2_, wh[1][2], vzero);
        azB_ = MF(h3_, wh[1][3], azB_);
        f32x4 gn_ = MF(h0_, wh[2][0], vd_gh);
        gn_ = MF(h1_, wh[2][1], gn_);
        f32x4 gnB_ = MF(h2_, wh[2][2], vzero);
        gnB_ = MF(h3_, wh[2][3], gnB_);
        #pragma unroll
        for (int e_ = 0; e_ < 2; ++e_) {
            const int rg_ = 2 * e_;
            const float r_ = sig2(ar_[rg_] + arB_[rg_]);
            const float z_ = sig2(az_[rg_] + azB_[rg_]);
            const float n_ = tanh2(c_n0 + r_ * (gn_[rg_] + gnB_[rg_]));
            const float h_ = n_ + z_ * (hold[e_] - n_);
            hold[e_] = h_;
            hbuf1[(2 * quad + e_) * HS + j] = (_Float16)h_;
        }
    }
    __syncthreads();

    // Step C: fold W2 = dWih*linW. r/z: wh <- fp16(S1*(dWhh + W2));
    // n: wxn <- fp16(S2*W2). (w2lds aliases xchunk; x is dead.)
    {
        const int kk = ((wv & 1) << 6) | ln;      // 0..127, lane's W2 column
        const int jb = (wv >> 1) * 32;            // 4 wave-pairs x 32 rows = 128
        float lc[X_DIM];
        #pragma unroll
        for (int m = 0; m < X_DIM; ++m) lc[m] = linW[m * H_DIM + kk];

        // gate 0 (r): combined
        #pragma unroll 1
        for (int jj = 0; jj < 32; ++jj) {
            const int jr = __builtin_amdgcn_readfirstlane(jb + jj);
            const float* dwr = dWih + (size_t)jr * X_DIM;
            float sacc = dWhh[(size_t)jr * H_DIM + kk];
            #pragma unroll
            for (int m = 0; m < X_DIM; ++m) sacc += dwr[m] * lc[m];
            w2lds[jr * H_DIM + kk] = (_Float16)(S1 * sacc);
        }
        __syncthreads();
        #pragma unroll
        for (int c = 0; c < 4; ++c)
            wh[0][c] = *(const half8*)&w2lds[j * H_DIM + c * 32 + quad * 8];
        __syncthreads();

        // gate 1 (z): combined
        #pragma unroll 1
        for (int jj = 0; jj < 32; ++jj) {
            const int jr = __builtin_amdgcn_readfirstlane(jb + jj);
            const float* dwr = dWih + (size_t)(H_DIM + jr) * X_DIM;
            float sacc = dWhh[(size_t)(H_DIM + jr) * H_DIM + kk];
            #pragma unroll
            for (int m = 0; m < X_DIM; ++m) sacc += dwr[m] * lc[m];
            w2lds[jr * H_DIM + kk] = (_Float16)(S1 * sacc);
        }
        __syncthreads();
        #pragma unroll
        for (int c = 0; c < 4; ++c)
            wh[1][c] = *(const half8*)&w2lds[j * H_DIM + c * 32 + quad * 8];
        __syncthreads();

        // gate 2 (n): W2 only (wh[2] stays pure scaled dWhh)
        #pragma unroll 1
        for (int jj = 0; jj < 32; ++jj) {
            const int jr = __builtin_amdgcn_readfirstlane(jb + jj);
            const float* dwr = dWih + (size_t)(2 * H_DIM + jr) * X_DIM;
            float sacc = 0.0f;
            #pragma unroll
            for (int m = 0; m < X_DIM; ++m) sacc += dwr[m] * lc[m];
            w2lds[jr * H_DIM + kk] = (_Float16)(S2 * sacc);
        }
        __syncthreads();
        #pragma unroll
        for (int c = 0; c < 4; ++c)
            wxn[c] = *(const half8*)&w2lds[j * H_DIM + c * 32 + quad * 8];
        __syncthreads();
    }

    // Step D: linear head frags + folded biases for t>=1.
    const int nlin = wv * 16 + mrow;          // waves 0..2 cover cols 0..47
    const bool nv = (wv < 3) && (nlin < X_DIM);
    float lb = 0.0f;
    {
        const float* lr = linW + (size_t)(nv ? nlin : 0) * H_DIM;
        #pragma unroll
        for (int c = 0; c < 4; ++c) {
            const int kb = c * 32 + quad * 8;
            half8 v;
            #pragma unroll
            for (int e = 0; e < 8; ++e)
                v[e] = nv ? (_Float16)lr[kb + e] : (_Float16)0.0f;
            wl[c] = v;
        }
        if (nv) lb = linb[nlin];
    }
    float db_r, db_z, db_gi;
    {
        float bf[3];
        #pragma unroll
        for (int p = 0; p < 3; ++p) {
            const float* dwr = dWih + (size_t)(p * H_DIM + j) * X_DIM;
            float sacc = 0.0f;
            #pragma unroll
            for (int m = 0; m < X_DIM; ++m) sacc += linb[m] * dwr[m];
            bf[p] = sacc;
        }
        db_r  = c_r0 + S1 * bf[0];
        db_z  = c_z0 + S1 * bf[1];
        db_gi = c_n0 + S2 * bf[2];
    }
    const f32x4 vd_r  = { db_r, db_r, db_r, db_r };
    const f32x4 vd_z  = { db_z, db_z, db_z, db_z };
    const f32x4 vd_gi = { db_gi, db_gi, db_gi, db_gi };
    const f32x4 vb_lb = { lb, lb, lb, lb };

    const size_t obase0 = ((size_t)(b0 + 2 * quad)     * T_SEQ) * X_DIM + nlin;
    const size_t obase1 = ((size_t)(b0 + 2 * quad + 1) * T_SEQ) * X_DIM + nlin;

    // ================= decoder (t=1..127, 63 unrolled pairs + tail) ========
    #pragma unroll 1
    for (int i = 0; i < 63; ++i) {
        DEC_STEP(hbuf1, hbuf0, 2 * i);        // t = 2i+1, stores o_{2i}
        DEC_STEP(hbuf0, hbuf1, 2 * i + 1);    // t = 2i+2, stores o_{2i+1}
    }
    DEC_STEP(hbuf1, hbuf0, 126);              // t = 127, stores o_126; d_128 -> hbuf0

    // tail projection: o_127 = d_128 @ linW^T + lb (d_128 in hbuf0; the
    // final LDS_BARRIER made those writes visible)
    if (wv < 3) {
        const _Float16* hb_ = hbuf0 + arow * HS + quad * 8;
        half8 h0_ = *(const half8*)(hb_ + 0 * 32);
        half8 h1_ = *(const half8*)(hb_ + 1 * 32);
        half8 h2_ = *(const half8*)(hb_ + 2 * 32);
        half8 h3_ = *(const half8*)(hb_ + 3 * 32);
        f32x4 al_ = MF(h0_, wl[0], vb_lb);
        al_ = MF(h1_, wl[1], al_);
        f32x4 alB_ = MF(h2_, wl[2], vzero);
        alB_ = MF(h3_, wl[3], alB_);
        if (nv) {
            out[obase0 + (size_t)(T_SEQ - 1) * X_DIM] = al_[0] + alB_[0];
            out[obase1 + (size_t)(T_SEQ - 1) * X_DIM] = al_[2] + alB_[2];
        }
    }
}

extern "C" void kernel_launch(void* const* d_in, const int* in_sizes, int n_in,
                              void* d_out, int out_size, void* d_ws, size_t ws_size,
                              hipStream_t stream) {
    (void)in_sizes; (void)n_in; (void)d_ws; (void)ws_size; (void)out_size;
    const float* x    = (const float*)d_in[0];
    const float* eWih = (const float*)d_in[1];
    const float* eWhh = (const float*)d_in[2];
    const float* ebih = (const float*)d_in[3];
    const float* ebhh = (const float*)d_in[4];
    const float* dWih = (const float*)d_in[5];
    const float* dWhh = (const float*)d_in[6];
    const float* dbih = (const float*)d_in[7];
    const float* dbhh = (const float*)d_in[8];
    const float* linW = (const float*)d_in[9];
    const float* linb = (const float*)d_in[10];
    float* out = (float*)d_out;

    rae_gru_kernel<<<dim3(B_TOT / BT), dim3(512), 0, stream>>>(
        x, eWih, eWhh, ebih, ebhh, dWih, dWhh, dbih, dbhh, linW, linb, out);
}